// Round 7
// baseline (225.277 us; speedup 1.0000x reference)
//
#include <hip/hip_runtime.h>
#include <hip/hip_bf16.h>

// CombinedModel R7: R6 persistent-wave pipeline, minus redundant LDS drains.
//   All LDS traffic is wave-private; DS pipe is in-order within a wave and the
//   compiler conservatively orders may-alias __shared__ accesses + inserts
//   fine-grained lgkmcnt before data use. So the explicit lgkmcnt(0) drains
//   (R6's lds_fence, ~10/chunk) are pure serialization -> replaced with bare
//   wave_barrier (compiler-motion guard only). Grid cap 1024 -> 2048 blocks
//   for residency slack + tail balance. Numerics identical to R6.

typedef __attribute__((ext_vector_type(2))) float f32x2;
typedef __attribute__((ext_vector_type(4))) float f32x4;
typedef __attribute__((ext_vector_type(4))) int   i32x4;
typedef __attribute__((ext_vector_type(8))) short s16x8;

#define GRID_W  2048
#define LSTR    36   // lat row stride (dwords): 144 B rows, 16B-aligned
#define PSTR    68   // h row stride (dwords): 272 B rows, 16B-aligned
#define SEL_HI  0x05040100u
#define SEL_LO  0x07060302u

static __device__ __forceinline__ unsigned bits_bf2(__hip_bfloat162 h) {
    union { __hip_bfloat162 b; unsigned u; } cv; cv.b = h; return cv.u;
}
// split (v0,v1) into bf16 hi + bf16 lo residual; packed dword_i = hi_i | lo_i<<16
static __device__ __forceinline__ void split2_packed(float v0, float v1, unsigned &p0, unsigned &p1) {
    float2 f; f.x = v0; f.y = v1;
    unsigned hu = bits_bf2(__float22bfloat162_rn(f));
    float2 d;
    d.x = v0 - __uint_as_float(hu << 16);
    d.y = v1 - __uint_as_float(hu & 0xffff0000u);
    unsigned lu = bits_bf2(__float22bfloat162_rn(d));
    p0 = (hu & 0xffffu) | (lu << 16);
    p1 = (hu >> 16) | (lu & 0xffff0000u);
}
static __device__ __forceinline__ s16x8 unpack8(uint4 q0, uint4 q1, unsigned sel) {
    union { unsigned u[4]; s16x8 v; } r;
    r.u[0] = __builtin_amdgcn_perm(q0.y, q0.x, sel);
    r.u[1] = __builtin_amdgcn_perm(q0.w, q0.z, sel);
    r.u[2] = __builtin_amdgcn_perm(q1.y, q1.x, sel);
    r.u[3] = __builtin_amdgcn_perm(q1.w, q1.z, sel);
    return r.v;
}
// single-bf16 weight fragment: 8 consecutive fp32 -> 8 bf16 (rtn)
static __device__ __forceinline__ s16x8 load_wbf(const float* p) {
    f32x4 a = ((const f32x4*)p)[0];
    f32x4 b = ((const f32x4*)p)[1];
    union { unsigned u[4]; s16x8 v; } r;
    float2 f;
    f.x = a.x; f.y = a.y; r.u[0] = bits_bf2(__float22bfloat162_rn(f));
    f.x = a.z; f.y = a.w; r.u[1] = bits_bf2(__float22bfloat162_rn(f));
    f.x = b.x; f.y = b.y; r.u[2] = bits_bf2(__float22bfloat162_rn(f));
    f.x = b.z; f.y = b.w; r.u[3] = bits_bf2(__float22bfloat162_rn(f));
    return r.v;
}
// compiler-motion guard only: HW DS pipe is in-order within a wave, and all
// LDS buffers here are wave-private, so no lgkmcnt drain is needed.
static __device__ __forceinline__ void lds_order() {
    __builtin_amdgcn_wave_barrier();
}

__global__ __launch_bounds__(256, 2) void fused_persistent(
    const float* __restrict__ x,          // [N,2]
    const float* __restrict__ positions,  // [N_POS,2]
    const int*   __restrict__ nbmap,      // [H,W,4]
    const float* __restrict__ emb,        // [N_POS,32]
    const float* __restrict__ W1,         // [64,32]
    const float* __restrict__ b1,         // [64]
    const float* __restrict__ W2,         // [64,64]
    const float* __restrict__ b2,         // [64]
    const float* __restrict__ W3,         // [3,64]
    const float* __restrict__ b3,         // [3]
    const float* __restrict__ mu,         // [3]
    const float* __restrict__ sd,         // [3]
    float* __restrict__ out,              // [N,3]
    int npts)
{
    const int tid  = threadIdx.x;
    const int w    = tid >> 6;
    const int lid  = tid & 63;
    const int quad = lid >> 4;
    const int m16  = lid & 15;
    const int c8   = lid & 7;    // gather: channel group (channels 4*c8 .. 4*c8+3)
    const int pr   = lid >> 3;   // gather: point row within pass (0..7)

    const int nwav = gridDim.x * 4;
    const int wgid = blockIdx.x * 4 + w;
    const int NCH  = (npts + 31) >> 5;
    if (wgid >= NCH) return;     // no block barriers anywhere: safe

    __shared__ __align__(16) unsigned lat_lds[4 * 32 * LSTR];   // 18.4 KB
    unsigned* latw = lat_lds + w * 32 * LSTR;   // wave-private 32-row slab
    unsigned* hb   = latw;                      // h-buffer overlays dead lat slab

    const f32x2* Xv  = (const f32x2*)x;
    const f32x2* Pv  = (const f32x2*)positions;
    const i32x4* NBq = (const i32x4*)nbmap;

    // ---- per-wave weights: A-split/W-single -> single-bf16 B-frags ----
    s16x8 w1f[4];
#pragma unroll
    for (int nt = 0; nt < 4; ++nt)
        w1f[nt] = load_wbf(W1 + (nt * 16 + m16) * 32 + quad * 8);
    s16x8 w2f[2][4];
#pragma unroll
    for (int s = 0; s < 2; ++s)
#pragma unroll
        for (int nt = 0; nt < 4; ++nt)
            w2f[s][nt] = load_wbf(W2 + (nt * 16 + m16) * 64 + s * 32 + quad * 8);
    s16x8 w3f[2];
#pragma unroll
    for (int s = 0; s < 2; ++s) {
        if (m16 < 3) {
            w3f[s] = load_wbf(W3 + m16 * 64 + s * 32 + quad * 8);
        } else {
            s16x8 z = {0, 0, 0, 0, 0, 0, 0, 0};
            w3f[s] = z;
        }
    }
    float b1v[4], b2v[4];
#pragma unroll
    for (int nt = 0; nt < 4; ++nt) { b1v[nt] = b1[nt * 16 + m16]; b2v[nt] = b2[nt * 16 + m16]; }
    const int mm = (m16 < 3) ? m16 : 0;
    const float b3m = b3[mm], sdm = sd[mm], mum = mu[mm];

    // ---- pipeline prologue: x + nbmap for first chunk ----
    f32x2 xv[4], xvn[4];
    i32x4 nb[4], nbn[4];
#pragma unroll
    for (int p = 0; p < 4; ++p) {
        int g = wgid * 32 + p * 8 + pr;
        g = (g < npts) ? g : (npts - 1);
        xv[p] = Xv[g];
    }
#pragma unroll
    for (int p = 0; p < 4; ++p) {
        int i0 = (int)xv[p].x, i1 = (int)xv[p].y;   // x >= 0: trunc == floor
        nb[p] = NBq[i0 * GRID_W + i1];
    }

    for (int c = wgid; c < NCH; c += nwav) {
        const int cn = c + nwav;
        const bool hn = (cn < NCH);

        // issue NEXT chunk's x loads now: consumed ~1 chunk later
        if (hn) {
#pragma unroll
            for (int p = 0; p < 4; ++p) {
                int g = cn * 32 + p * 8 + pr;
                g = (g < npts) ? g : (npts - 1);
                xvn[p] = Xv[g];
            }
        }

        // ---- gather chunk c (nb[] already resident; pos/emb = 1 exposed RT) ----
#pragma unroll
        for (int p = 0; p < 4; ++p) {
            f32x2 xvp = xv[p];
            float f0 = (float)(int)xvp.x, f1 = (float)(int)xvp.y;
            i32x4 n4 = nb[p];
            int ids[4] = {n4.x, n4.y, n4.z, n4.w};
            float a0 = 0.f, a1 = 0.f, a2 = 0.f, a3 = 0.f;
#pragma unroll
            for (int k = 0; k < 4; ++k) {
                f32x2 pp = Pv[ids[k]];
                float dx = pp.x - f0, dy = pp.y - f1;
                float dist = sqrtf(dx * dx + dy * dy);
                f32x4 e = *(const f32x4*)(emb + ids[k] * 32 + c8 * 4); // 8 lanes = full 128B row
                a0 = fmaf(dist, e.x, a0); a1 = fmaf(dist, e.y, a1);
                a2 = fmaf(dist, e.z, a2); a3 = fmaf(dist, e.w, a3);
            }
            unsigned p0, p1, p2, p3;
            split2_packed(a0, a1, p0, p1);
            split2_packed(a2, a3, p2, p3);
            uint4 pv; pv.x = p0; pv.y = p1; pv.z = p2; pv.w = p3;
            *(uint4*)(latw + (p * 8 + pr) * LSTR + c8 * 4) = pv;
        }
        lds_order();

        // pre-read BOTH tiles' A-frags before hb overlay
        s16x8 AH[2], AL[2];
#pragma unroll
        for (int t = 0; t < 2; ++t) {
            const unsigned* ap = latw + (t * 16 + m16) * LSTR + quad * 8;
            uint4 q0 = *(const uint4*)ap;
            uint4 q1 = *(const uint4*)(ap + 4);
            AH[t] = unpack8(q0, q1, SEL_HI);
            AL[t] = unpack8(q0, q1, SEL_LO);
        }
        lds_order();

        // issue NEXT chunk's nbmap loads (xvn arrived during gather);
        // their round-trip hides under the MLP below
        if (hn) {
#pragma unroll
            for (int p = 0; p < 4; ++p) {
                int i0 = (int)xvn[p].x, i1 = (int)xvn[p].y;
                nbn[p] = NBq[i0 * GRID_W + i1];
            }
        }

        // ---- MLP: 2 tiles of 16 points ----
#pragma unroll
        for (int t = 0; t < 2; ++t) {
            s16x8 ah = AH[t], al = AL[t];
            // L1: (ah+al) @ W1 -> 8 MFMA
            f32x4 c1[4];
#pragma unroll
            for (int nt = 0; nt < 4; ++nt) {
                f32x4 cc = {0.f, 0.f, 0.f, 0.f};
                cc = __builtin_amdgcn_mfma_f32_16x16x32_bf16(al, w1f[nt], cc, 0, 0, 0);
                cc = __builtin_amdgcn_mfma_f32_16x16x32_bf16(ah, w1f[nt], cc, 0, 0, 0);
                c1[nt] = cc;
            }
            lds_order();
#pragma unroll
            for (int nt = 0; nt < 4; ++nt)
#pragma unroll
                for (int r = 0; r < 4; r += 2) {
                    float v0 = fmaxf(c1[nt][r]     + b1v[nt], 0.f);
                    float v1 = fmaxf(c1[nt][r + 1] + b1v[nt], 0.f);
                    unsigned p0, p1; split2_packed(v0, v1, p0, p1);
                    hb[(quad * 4 + r)     * PSTR + nt * 16 + m16] = p0;
                    hb[(quad * 4 + r + 1) * PSTR + nt * 16 + m16] = p1;
                }
            lds_order();

            // L2: (a2h+a2l) @ W2 -> 16 MFMA
            f32x4 c2[4] = {{0.f,0.f,0.f,0.f},{0.f,0.f,0.f,0.f},{0.f,0.f,0.f,0.f},{0.f,0.f,0.f,0.f}};
#pragma unroll
            for (int s = 0; s < 2; ++s) {
                const unsigned* rp = hb + m16 * PSTR + s * 32 + quad * 8;
                uint4 h0 = *(const uint4*)rp;
                uint4 h1 = *(const uint4*)(rp + 4);
                s16x8 a2h = unpack8(h0, h1, SEL_HI);
                s16x8 a2l = unpack8(h0, h1, SEL_LO);
#pragma unroll
                for (int nt = 0; nt < 4; ++nt) {
                    c2[nt] = __builtin_amdgcn_mfma_f32_16x16x32_bf16(a2l, w2f[s][nt], c2[nt], 0, 0, 0);
                    c2[nt] = __builtin_amdgcn_mfma_f32_16x16x32_bf16(a2h, w2f[s][nt], c2[nt], 0, 0, 0);
                }
            }
            lds_order();   // h1 reads issued before h2 writes (DS in-order per wave)
#pragma unroll
            for (int nt = 0; nt < 4; ++nt)
#pragma unroll
                for (int r = 0; r < 4; r += 2) {
                    float v0 = fmaxf(c2[nt][r]     + b2v[nt], 0.f);
                    float v1 = fmaxf(c2[nt][r + 1] + b2v[nt], 0.f);
                    unsigned p0, p1; split2_packed(v0, v1, p0, p1);
                    hb[(quad * 4 + r)     * PSTR + nt * 16 + m16] = p0;
                    hb[(quad * 4 + r + 1) * PSTR + nt * 16 + m16] = p1;
                }
            lds_order();

            // L3: (a3h+a3l) @ W3p -> 4 MFMA (rows 0..2 valid)
            f32x4 c3 = {0.f, 0.f, 0.f, 0.f};
#pragma unroll
            for (int s = 0; s < 2; ++s) {
                const unsigned* rp = hb + m16 * PSTR + s * 32 + quad * 8;
                uint4 h0 = *(const uint4*)rp;
                uint4 h1 = *(const uint4*)(rp + 4);
                s16x8 a3h = unpack8(h0, h1, SEL_HI);
                s16x8 a3l = unpack8(h0, h1, SEL_LO);
                c3 = __builtin_amdgcn_mfma_f32_16x16x32_bf16(a3l, w3f[s], c3, 0, 0, 0);
                c3 = __builtin_amdgcn_mfma_f32_16x16x32_bf16(a3h, w3f[s], c3, 0, 0, 0);
            }
            lds_order();   // h2 reads issued before next tile's h1 writes
#pragma unroll
            for (int r = 0; r < 4; ++r) {
                float v = (c3[r] + b3m) * sdm + mum;
                v = fminf(fmaxf(v, 0.f), 1.f);   // finite inputs: no NaN path
                int gpt = c * 32 + t * 16 + quad * 4 + r;
                if (m16 < 3 && gpt < npts) out[(size_t)gpt * 3 + m16] = v;
            }
        }

        // rotate pipeline registers
        if (hn) {
#pragma unroll
            for (int p = 0; p < 4; ++p) { xv[p] = xvn[p]; nb[p] = nbn[p]; }
        }
    }
}

extern "C" void kernel_launch(void* const* d_in, const int* in_sizes, int n_in,
                              void* d_out, int out_size, void* d_ws, size_t ws_size,
                              hipStream_t stream) {
    const float* x         = (const float*)d_in[0];
    const float* positions = (const float*)d_in[1];
    const int*   nbmap     = (const int*)d_in[2];
    const float* emb       = (const float*)d_in[3];
    const float* W1        = (const float*)d_in[4];
    const float* b1        = (const float*)d_in[5];
    const float* W2        = (const float*)d_in[6];
    const float* b2        = (const float*)d_in[7];
    const float* W3        = (const float*)d_in[8];
    const float* b3        = (const float*)d_in[9];
    const float* mu        = (const float*)d_in[10];
    const float* sd        = (const float*)d_in[11];
    float* out = (float*)d_out;

    int npts = in_sizes[0] / 2;
    int nch = (npts + 31) / 32;
    int blocks = 2048;                 // residency slack + tail balance
    int maxb = (nch + 3) / 4;
    if (blocks > maxb) blocks = maxb;
    fused_persistent<<<blocks, 256, 0, stream>>>(x, positions, nbmap, emb,
                                                 W1, b1, W2, b2, W3, b3, mu, sd,
                                                 out, npts);
}